// Round 7
// baseline (554.063 us; speedup 1.0000x reference)
//
#include <hip/hip_runtime.h>
#include <hip/hip_bf16.h>

typedef _Float16 f16;
typedef _Float16 f16x8 __attribute__((ext_vector_type(8)));
typedef float f32x4 __attribute__((ext_vector_type(4)));

#define TOKS 8192
#define DDIM 1024
#define CHDIM 256

// DAG: preds(v) ⊆ {v-1, v-2, 0, 1}. Edge order (sorted preds): extras(0[,1]) first, then v-2, then v-1.
__device__ __constant__ int c_OFF[16]  = {0,0,1,3,5,7,9,11,13,15,17,19,21,23,25,28};
__device__ __constant__ int c_NP[16]   = {0,1,2,2,2,2,2,2,2,2,2,2,2,2,3,4};
__device__ __constant__ int c_RROW[32] = {4, 8,9, 12,13, 16,17, 20,21, 24,25, 28,29, 32,33, 36,37, 40,41, 44,45, 48,49, 52,53, 56,57,58, 60,61,62,63};

__device__ __forceinline__ f16x8 sp8(f16 w){
  f16x8 r;
  #pragma unroll
  for (int j=0;j<8;++j) r[j]=w;
  return r;
}

// ---------------- kernel 1: prep ----------------
// blocks 0..2047: LN(x)->f16 xn + router sigmoids (f32-exact). 2048..4095: pack W1. 4096..6143: pack W2.
__global__ __launch_bounds__(256) void k_prep(const float* __restrict__ x, const float* __restrict__ g,
                                              const float* __restrict__ b, f16* __restrict__ xn,
                                              const float* __restrict__ rw, const float* __restrict__ rb,
                                              float* __restrict__ wsig,
                                              const float* __restrict__ w1, const float* __restrict__ w2,
                                              f16* __restrict__ w1p, f16* __restrict__ w2p){
  const int blk = blockIdx.x, tid = threadIdx.x;
  if (blk < 2048){
    const int lane = tid & 63, wv = tid >> 6;
    const int tk = blk*4 + wv;
    const float* xp = x + (size_t)tk*DDIM + lane*16;
    float xv[16];
    #pragma unroll
    for (int j=0;j<16;j+=4){ const float4 f=*(const float4*)(xp+j); xv[j]=f.x; xv[j+1]=f.y; xv[j+2]=f.z; xv[j+3]=f.w; }
    float s=0.f, q=0.f;
    #pragma unroll
    for (int j=0;j<16;++j){ s += xv[j]; q += xv[j]*xv[j]; }
    #pragma unroll
    for (int m=1;m<64;m<<=1){ s += __shfl_xor(s,m); q += __shfl_xor(q,m); }
    const float mu = s*(1.f/DDIM);
    const float rs = rsqrtf(q*(1.f/DDIM) - mu*mu + 1e-5f);
    #pragma unroll
    for (int j=0;j<16;j+=4){
      const float4 gg=*(const float4*)(g + lane*16 + j);
      const float4 bb=*(const float4*)(b + lane*16 + j);
      xv[j]   = (xv[j]  -mu)*rs*gg.x + bb.x;
      xv[j+1] = (xv[j+1]-mu)*rs*gg.y + bb.y;
      xv[j+2] = (xv[j+2]-mu)*rs*gg.z + bb.z;
      xv[j+3] = (xv[j+3]-mu)*rs*gg.w + bb.w;
    }
    f16x8 o0, o1;
    #pragma unroll
    for (int j=0;j<8;++j){ o0[j] = (f16)xv[j]; o1[j] = (f16)xv[8+j]; }
    *(f16x8*)(xn + (size_t)tk*DDIM + lane*16)     = o0;
    *(f16x8*)(xn + (size_t)tk*DDIM + lane*16 + 8) = o1;
    for (int e=0;e<32;++e){
      const int row = c_RROW[e];
      const float* rp = rw + (size_t)row*DDIM + lane*16;
      float d = 0.f;
      #pragma unroll
      for (int j=0;j<16;j+=4){
        const float4 f=*(const float4*)(rp+j);
        d += xv[j]*f.x + xv[j+1]*f.y + xv[j+2]*f.z + xv[j+3]*f.w;
      }
      #pragma unroll
      for (int m=1;m<64;m<<=1) d += __shfl_xor(d,m);
      if (lane==0) wsig[tk*32 + e] = 1.f/(1.f + expf(-(d + rb[row])));
    }
  } else if (blk < 4096){
    // W1 pack for 8-wave layout: c = v<<15 | wv<<12 | ic<<7 | nf<<6 | g4<<4 | l15
    const int c = (blk-2048)*256 + tid;
    const int l15 = c & 15, g4 = (c>>4)&3, nf = (c>>6)&1, ic = (c>>7)&31, wvv = (c>>12)&7, v = c>>15;
    const float* s = w1 + (size_t)v*262144 + (size_t)(wvv*32 + nf*16 + l15)*1024 + ic*32 + g4*8;
    const float4 a = *(const float4*)s, b4 = *(const float4*)(s+4);
    f16x8 o;
    o[0]=(f16)a.x; o[1]=(f16)a.y; o[2]=(f16)a.z; o[3]=(f16)a.w;
    o[4]=(f16)b4.x; o[5]=(f16)b4.y; o[6]=(f16)b4.z; o[7]=(f16)b4.w;
    *(f16x8*)(w1p + (size_t)c*8) = o;
  } else {
    // W2 pack: c = v<<15 | wv<<12 | ks<<9 | nf<<6 | g4<<4 | l15
    const int c = (blk-4096)*256 + tid;
    const int l15 = c & 15, g4 = (c>>4)&3, nf = (c>>6)&7, ks = (c>>9)&7, wvv = (c>>12)&7, v = c>>15;
    const float* s = w2 + (size_t)v*262144 + (size_t)(wvv*128 + nf*16 + l15)*256 + ks*32 + g4*8;
    const float4 a = *(const float4*)s, b4 = *(const float4*)(s+4);
    f16x8 o;
    o[0]=(f16)a.x; o[1]=(f16)a.y; o[2]=(f16)a.z; o[3]=(f16)a.w;
    o[4]=(f16)b4.x; o[5]=(f16)b4.y; o[6]=(f16)b4.z; o[7]=(f16)b4.w;
    *(f16x8*)(w2p + (size_t)c*8) = o;
  }
}

// ---------------- kernel 2: fused persistent MoE-DAG ----------------
// 512 blocks x 512 threads (8 waves); 2 blocks/CU for cross-block latency hiding.
// Block owns 16 tokens. Inter-node flow in 2 LDS ping-pong buffers; only O_0,O_1 via global.
__global__ __launch_bounds__(512,4) void k_moe(
    const f16* __restrict__ xn, const f16* __restrict__ w1p, const f16* __restrict__ w2p,
    const float* __restrict__ fc1b, const float* __restrict__ lng, const float* __restrict__ lnb,
    const float* __restrict__ f2bias, const float* __restrict__ wsigG,
    const float* __restrict__ x, float* __restrict__ out, f16* __restrict__ gouts)
{
  __shared__ f16 wsg[16][32];                    // router sigmoids (f16)
  __shared__ __align__(16) f16 Pbuf0[16*1032];   // ping-pong O_{v-1}/O_{v-2}+Ain
  __shared__ __align__(16) f16 Pbuf1[16*1032];
  __shared__ __align__(16) f16 hln[16*264];      // LN'd hidden [16][256] pad->264
  __shared__ float part[16][8][2];               // per-token LN partials per wave

  const int tid = threadIdx.x;
  const int lane = tid & 63, wv = tid >> 6;      // wv 0..7
  const int l15 = lane & 15, g4 = (lane >> 4) & 3;
  const int blk = blockIdx.x, tok0 = blk * 16;
  const f32x4 fzero = {0.f,0.f,0.f,0.f};

  wsg[tid>>5][tid&31] = (f16)wsigG[tok0*32 + tid];

  f16* Pp = Pbuf0;   // O_{v-1} (garbage at v=0, unused)
  f16* Pc = Pbuf1;   // Ain target; holds O_{v-2} on entry (v>=2)

  for (int v=0; v<16; ++v){
    // ---- stage: build Ain into Pc (in-place over O_{v-2}); packed f16 math ----
    if (v == 0){
      #pragma unroll
      for (int p=0;p<4;++p){
        const int c = tid + p*512, t = c>>7, c8 = (c&127)*8;
        *(f16x8*)&Pc[t*1032 + c8] = *(const f16x8*)(xn + (size_t)(tok0+t)*DDIM + c8);
      }
    } else {
      const int np = c_NP[v], off = c_OFF[v];
      const int ech = off + np - 1, ev2 = off + np - 2, nex = np - 2;
      #pragma unroll
      for (int p=0;p<4;++p){
        const int c = tid + p*512, t = c>>7, c8 = (c&127)*8;
        const f16x8 pv = *(const f16x8*)&Pp[t*1032 + c8];
        if (v <= 2)  // save O_0 (v=1) / O_1 (v=2) for nodes 14/15
          *(f16x8*)(gouts + (size_t)(v-1)*TOKS*DDIM + (size_t)(tok0+t)*DDIM + c8) = pv;
        f16x8 acc = sp8(wsg[t][ech]) * pv;
        if (np >= 2){
          const f16x8 p2 = *(const f16x8*)&Pc[t*1032 + c8];
          acc += sp8(wsg[t][ev2]) * p2;
        }
        if (nex >= 1){
          const f16x8 e0 = *(const f16x8*)(gouts + (size_t)(tok0+t)*DDIM + c8);
          acc += sp8(wsg[t][off]) * e0;
        }
        if (nex >= 2){
          const f16x8 e1 = *(const f16x8*)(gouts + (size_t)TOKS*DDIM + (size_t)(tok0+t)*DDIM + c8);
          acc += sp8(wsg[t][off+1]) * e1;
        }
        *(f16x8*)&Pc[t*1032 + c8] = acc;
      }
    }
    __syncthreads();

    // ---- fc1: [16x1024]x[1024x256]; wave = 32 cols (2 N-frags); compiler-pipelined ----
    const f16* bp1 = w1p + (size_t)(v*8 + wv)*32768 + lane*8;
    f32x4 acc1[2] = {fzero, fzero};
    #pragma unroll 4
    for (int ic=0; ic<32; ++ic){
      const f16x8 a0 = *(const f16x8*)&Pc[l15*1032 + ic*32 + g4*8];
      const f16x8 b0 = *(const f16x8*)(bp1 + (ic*2  )*512);
      const f16x8 b1 = *(const f16x8*)(bp1 + (ic*2+1)*512);
      acc1[0] = __builtin_amdgcn_mfma_f32_16x16x32_f16(a0, b0, acc1[0], 0,0,0);
      acc1[1] = __builtin_amdgcn_mfma_f32_16x16x32_f16(a0, b1, acc1[1], 0,0,0);
    }

    // ---- epilogue: bias + exact gelu + LN(256) partials ----
    float fb[2], lg[2], lb[2];
    #pragma unroll
    for (int nf=0;nf<2;++nf){
      const int c1 = wv*32 + nf*16 + l15;
      fb[nf] = fc1b[v*CHDIM + c1];
      lg[nf] = lng[v*CHDIM + c1];
      lb[nf] = lnb[v*CHDIM + c1];
    }
    #pragma unroll
    for (int nf=0;nf<2;++nf)
      #pragma unroll
      for (int r=0;r<4;++r){
        const float h = acc1[nf][r] + fb[nf];
        acc1[nf][r] = 0.5f*h*(1.f + erff(h*0.70710678118654752f));
      }
    #pragma unroll
    for (int r=0;r<4;++r){
      float s = acc1[0][r] + acc1[1][r];
      float q = acc1[0][r]*acc1[0][r] + acc1[1][r]*acc1[1][r];
      #pragma unroll
      for (int m=1;m<16;m<<=1){ s += __shfl_xor(s,m); q += __shfl_xor(q,m); }
      if (l15==0){ const int t = g4*4 + r; part[t][wv][0]=s; part[t][wv][1]=q; }
    }
    __syncthreads();

    // ---- mu/rs inline + hln write ----
    #pragma unroll
    for (int r=0;r<4;++r){
      const int t = g4*4 + r;
      float s=0.f, q=0.f;
      #pragma unroll
      for (int w4=0; w4<4; ++w4){
        const float4 pq = *(const float4*)&part[t][w4*2][0];
        s += pq.x + pq.z; q += pq.y + pq.w;
      }
      const float mu = s*(1.f/CHDIM);
      const float rs = rsqrtf(q*(1.f/CHDIM) - mu*mu + 1e-5f);
      #pragma unroll
      for (int nf=0;nf<2;++nf)
        hln[t*264 + wv*32 + nf*16 + l15] = (f16)((acc1[nf][r]-mu)*rs*lg[nf] + lb[nf]);
    }
    __syncthreads();

    // ---- fc2: [16x256]x[256x1024]; wave = 128 cols (8 N-frags) ----
    const f16* bp2 = w2p + (size_t)(v*8 + wv)*32768 + lane*8;
    f32x4 acc2[8];
    #pragma unroll
    for (int i=0;i<8;++i) acc2[i] = fzero;
    #pragma unroll 2
    for (int ks=0; ks<8; ++ks){
      const f16x8 a0 = *(const f16x8*)&hln[l15*264 + ks*32 + g4*8];
      #pragma unroll
      for (int nf=0;nf<8;++nf){
        const f16x8 b = *(const f16x8*)(bp2 + (size_t)(ks*8 + nf)*512);
        acc2[nf] = __builtin_amdgcn_mfma_f32_16x16x32_f16(a0, b, acc2[nf], 0,0,0);
      }
    }
    // write O_v into Pc (+ terminal bias)
    #pragma unroll
    for (int nf=0;nf<8;++nf){
      const int c2 = wv*128 + nf*16 + l15;
      const float fb2 = (v==15) ? f2bias[c2] : 0.f;
      #pragma unroll
      for (int r=0;r<4;++r){
        const int t = g4*4 + r;
        Pc[t*1032 + c2] = (f16)(acc2[nf][r] + fb2);
      }
    }
    __syncthreads();   // O_v visible before next stage / terminal write

    if (v == 15){
      #pragma unroll
      for (int p=0;p<4;++p){
        const int c = tid + p*512, t = c>>7, c8 = (c&127)*8;
        const f16x8 val = *(const f16x8*)&Pc[t*1032 + c8];
        const size_t gi = (size_t)(tok0+t)*DDIM + c8;
        const float4 x0 = *(const float4*)(x+gi), x1 = *(const float4*)(x+gi+4);
        float4 o0, o1;
        o0.x = x0.x + (float)val[0]; o0.y = x0.y + (float)val[1];
        o0.z = x0.z + (float)val[2]; o0.w = x0.w + (float)val[3];
        o1.x = x1.x + (float)val[4]; o1.y = x1.y + (float)val[5];
        o1.z = x1.z + (float)val[6]; o1.w = x1.w + (float)val[7];
        *(float4*)(out+gi) = o0; *(float4*)(out+gi+4) = o1;
      }
    }
    f16* tmp = Pp; Pp = Pc; Pc = tmp;
  }
}

extern "C" void kernel_launch(void* const* d_in, const int* in_sizes, int n_in,
                              void* d_out, int out_size, void* d_ws, size_t ws_size,
                              hipStream_t stream) {
  (void)in_sizes; (void)n_in; (void)out_size; (void)ws_size;
  const float* x   = (const float*)d_in[0];
  const float* ng  = (const float*)d_in[1];
  const float* nb_ = (const float*)d_in[2];
  const float* w1  = (const float*)d_in[3];
  const float* f1b = (const float*)d_in[4];
  const float* lg  = (const float*)d_in[5];
  const float* lb  = (const float*)d_in[6];
  const float* w2  = (const float*)d_in[7];
  const float* f2b = (const float*)d_in[8];
  const float* rw  = (const float*)d_in[9];
  const float* rb  = (const float*)d_in[10];
  float* out = (float*)d_out;

  char* ws = (char*)d_ws;
  f16*  xnh  = (f16*)(ws);                                   // 16 MB
  f16*  w1p  = (f16*)(ws + 16777216);                        //  8 MB
  f16*  w2p  = (f16*)(ws + 16777216 + 8388608);              //  8 MB
  float* wsg = (float*)(ws + 16777216 + 8388608 + 8388608);  //  1 MB
  f16*  gouts= (f16*)(ws + 16777216 + 8388608 + 8388608 + 1048576); // 32 MB (O_0, O_1)

  k_prep<<<6144, 256, 0, stream>>>(x, ng, nb_, xnh, rw, rb, wsg, w1, w2, w1p, w2p);
  k_moe<<<512, 512, 0, stream>>>(xnh, w1p, w2p, f1b, lg, lb, f2b, wsg, x, out, gouts);
}

// Round 8
// 394.760 us; speedup vs baseline: 1.4035x; 1.4035x over previous
//
#include <hip/hip_runtime.h>
#include <hip/hip_bf16.h>

typedef _Float16 f16;
typedef _Float16 f16x8 __attribute__((ext_vector_type(8)));
typedef float f32x4 __attribute__((ext_vector_type(4)));

#define TOKS 8192
#define DDIM 1024
#define CHDIM 256

// DAG: preds(v) ⊆ {v-1, v-2, 0, 1}. Edge order (sorted preds): extras(0[,1]) first, then v-2, then v-1.
__device__ __constant__ int c_OFF[16]  = {0,0,1,3,5,7,9,11,13,15,17,19,21,23,25,28};
__device__ __constant__ int c_NP[16]   = {0,1,2,2,2,2,2,2,2,2,2,2,2,2,3,4};
__device__ __constant__ int c_RROW[32] = {4, 8,9, 12,13, 16,17, 20,21, 24,25, 28,29, 32,33, 36,37, 40,41, 44,45, 48,49, 52,53, 56,57,58, 60,61,62,63};

__device__ __forceinline__ f16x8 sp8(f16 w){
  f16x8 r;
  #pragma unroll
  for (int j=0;j<8;++j) r[j]=w;
  return r;
}

// ---------------- kernel 1: prep ----------------
// blocks 0..2047: LN(x)->f16 xn + router sigmoids (f32-exact). 2048..4095: pack W1. 4096..6143: pack W2.
// Packs target the 16-wave k_moe layout: per-(v,wave) contiguous 32KB streams of 1KB chunks.
__global__ __launch_bounds__(256) void k_prep(const float* __restrict__ x, const float* __restrict__ g,
                                              const float* __restrict__ b, f16* __restrict__ xn,
                                              const float* __restrict__ rw, const float* __restrict__ rb,
                                              float* __restrict__ wsig,
                                              const float* __restrict__ w1, const float* __restrict__ w2,
                                              f16* __restrict__ w1p, f16* __restrict__ w2p){
  const int blk = blockIdx.x, tid = threadIdx.x;
  if (blk < 2048){
    const int lane = tid & 63, wv = tid >> 6;
    const int tk = blk*4 + wv;
    const float* xp = x + (size_t)tk*DDIM + lane*16;
    float xv[16];
    #pragma unroll
    for (int j=0;j<16;j+=4){ const float4 f=*(const float4*)(xp+j); xv[j]=f.x; xv[j+1]=f.y; xv[j+2]=f.z; xv[j+3]=f.w; }
    float s=0.f, q=0.f;
    #pragma unroll
    for (int j=0;j<16;++j){ s += xv[j]; q += xv[j]*xv[j]; }
    #pragma unroll
    for (int m=1;m<64;m<<=1){ s += __shfl_xor(s,m); q += __shfl_xor(q,m); }
    const float mu = s*(1.f/DDIM);
    const float rs = rsqrtf(q*(1.f/DDIM) - mu*mu + 1e-5f);
    #pragma unroll
    for (int j=0;j<16;j+=4){
      const float4 gg=*(const float4*)(g + lane*16 + j);
      const float4 bb=*(const float4*)(b + lane*16 + j);
      xv[j]   = (xv[j]  -mu)*rs*gg.x + bb.x;
      xv[j+1] = (xv[j+1]-mu)*rs*gg.y + bb.y;
      xv[j+2] = (xv[j+2]-mu)*rs*gg.z + bb.z;
      xv[j+3] = (xv[j+3]-mu)*rs*gg.w + bb.w;
    }
    f16x8 o0, o1;
    #pragma unroll
    for (int j=0;j<8;++j){ o0[j] = (f16)xv[j]; o1[j] = (f16)xv[8+j]; }
    *(f16x8*)(xn + (size_t)tk*DDIM + lane*16)     = o0;
    *(f16x8*)(xn + (size_t)tk*DDIM + lane*16 + 8) = o1;
    for (int e=0;e<32;++e){
      const int row = c_RROW[e];
      const float* rp = rw + (size_t)row*DDIM + lane*16;
      float d = 0.f;
      #pragma unroll
      for (int j=0;j<16;j+=4){
        const float4 f=*(const float4*)(rp+j);
        d += xv[j]*f.x + xv[j+1]*f.y + xv[j+2]*f.z + xv[j+3]*f.w;
      }
      #pragma unroll
      for (int m=1;m<64;m<<=1) d += __shfl_xor(d,m);
      if (lane==0) wsig[tk*32 + e] = 1.f/(1.f + expf(-(d + rb[row])));
    }
  } else if (blk < 4096){
    // W1 pack: c = v<<15 | wv<<11 | ic<<6 | g4<<4 | l15
    const int c = (blk-2048)*256 + tid;
    const int l15 = c & 15, g4 = (c>>4)&3, ic = (c>>6)&31, wvv = (c>>11)&15, v = c>>15;
    const float* s = w1 + (size_t)v*262144 + (size_t)(wvv*16 + l15)*1024 + ic*32 + g4*8;
    const float4 a = *(const float4*)s, b4 = *(const float4*)(s+4);
    f16x8 o;
    o[0]=(f16)a.x; o[1]=(f16)a.y; o[2]=(f16)a.z; o[3]=(f16)a.w;
    o[4]=(f16)b4.x; o[5]=(f16)b4.y; o[6]=(f16)b4.z; o[7]=(f16)b4.w;
    *(f16x8*)(w1p + (size_t)c*8) = o;
  } else {
    // W2 pack: c = v<<15 | wv<<11 | ks<<8 | nf<<6 | g4<<4 | l15
    const int c = (blk-4096)*256 + tid;
    const int l15 = c & 15, g4 = (c>>4)&3, nf = (c>>6)&3, ks = (c>>8)&7, wvv = (c>>11)&15, v = c>>15;
    const float* s = w2 + (size_t)v*262144 + (size_t)(wvv*64 + nf*16 + l15)*256 + ks*32 + g4*8;
    const float4 a = *(const float4*)s, b4 = *(const float4*)(s+4);
    f16x8 o;
    o[0]=(f16)a.x; o[1]=(f16)a.y; o[2]=(f16)a.z; o[3]=(f16)a.w;
    o[4]=(f16)b4.x; o[5]=(f16)b4.y; o[6]=(f16)b4.z; o[7]=(f16)b4.w;
    *(f16x8*)(w2p + (size_t)c*8) = o;
  }
}

// ---------------- kernel 2: fused persistent MoE-DAG ----------------
// 256 blocks x 1024 threads (16 waves, 1 block/CU). Block owns 32 tokens, all 16 nodes.
// LDS ping-pong for inter-node flow; deep STATIC B-prefetch hoisted across barriers.
__global__ __launch_bounds__(1024,4) void k_moe(
    const f16* __restrict__ xn, const f16* __restrict__ w1p, const f16* __restrict__ w2p,
    const float* __restrict__ fc1b, const float* __restrict__ lng, const float* __restrict__ lnb,
    const float* __restrict__ f2bias, const float* __restrict__ wsigG,
    const float* __restrict__ x, float* __restrict__ out, f16* __restrict__ gouts)
{
  __shared__ f16 wsg[32][32];                    // router sigmoids (f16)
  __shared__ __align__(16) f16 Pbuf0[32*1032];   // ping-pong O_{v-1}/O_{v-2}+Ain
  __shared__ __align__(16) f16 Pbuf1[32*1032];
  __shared__ __align__(16) f16 hln[32*264];      // LN'd hidden [32][256] pad->264
  __shared__ float part[32][17][2];              // per-token LN partials per wave
  __shared__ float musq[32][2];                  // per-token {mu, rsqrt}

  const int tid = threadIdx.x;
  const int lane = tid & 63, wv = tid >> 6;      // wv 0..15
  const int l15 = lane & 15, g4 = (lane >> 4) & 3;
  const int blk = blockIdx.x, tok0 = blk * 32;
  const f32x4 fzero = {0.f,0.f,0.f,0.f};

  wsg[tid>>5][tid&31] = (f16)wsigG[tok0*32 + tid];

  f16* Pp = Pbuf0;   // O_{v-1} (garbage at v=0, unused)
  f16* Pc = Pbuf1;   // Ain target; holds O_{v-2} on entry (v>=2)

  for (int v=0; v<16; ++v){
    // ---- fc1 B prefetch: 12 chunks issued BEFORE stage (latency hides under stage+barrier) ----
    const f16* bp1 = w1p + (size_t)(v*16 + wv)*16384 + lane*8;
    f16x8 pb[12];
    #pragma unroll
    for (int j=0;j<12;++j) pb[j] = *(const f16x8*)(bp1 + j*512);

    // ---- stage: build Ain into Pc (in-place over O_{v-2}); packed f16 math ----
    if (v == 0){
      #pragma unroll
      for (int p=0;p<4;++p){
        const int c = tid + p*1024, t = c>>7, c8 = (c&127)*8;
        *(f16x8*)&Pc[t*1032 + c8] = *(const f16x8*)(xn + (size_t)(tok0+t)*DDIM + c8);
      }
    } else {
      const int np = c_NP[v], off = c_OFF[v];
      const int ech = off + np - 1, ev2 = off + np - 2, nex = np - 2;
      #pragma unroll
      for (int p=0;p<4;++p){
        const int c = tid + p*1024, t = c>>7, c8 = (c&127)*8;
        const f16x8 pv = *(const f16x8*)&Pp[t*1032 + c8];
        if (v <= 2)  // save O_0 (v=1) / O_1 (v=2) for nodes 14/15
          *(f16x8*)(gouts + (size_t)(v-1)*TOKS*DDIM + (size_t)(tok0+t)*DDIM + c8) = pv;
        f16x8 acc = sp8(wsg[t][ech]) * pv;
        if (np >= 2){
          const f16x8 p2 = *(const f16x8*)&Pc[t*1032 + c8];
          acc += sp8(wsg[t][ev2]) * p2;
        }
        if (nex >= 1){
          const f16x8 e0 = *(const f16x8*)(gouts + (size_t)(tok0+t)*DDIM + c8);
          acc += sp8(wsg[t][off]) * e0;
        }
        if (nex >= 2){
          const f16x8 e1 = *(const f16x8*)(gouts + (size_t)TOKS*DDIM + (size_t)(tok0+t)*DDIM + c8);
          acc += sp8(wsg[t][off+1]) * e1;
        }
        *(f16x8*)&Pc[t*1032 + c8] = acc;
      }
    }
    __syncthreads();

    // ---- fc1: [32x1024]x[1024x256]; wave = 16 cols (1 N-frag), both M-frags; full unroll ----
    f32x4 acc1[2] = {fzero, fzero};
    #pragma unroll
    for (int ic=0; ic<32; ++ic){
      const f16x8 b = pb[ic%12];
      if (ic < 20) pb[ic%12] = *(const f16x8*)(bp1 + (ic+12)*512);
      const f16x8 a0 = *(const f16x8*)&Pc[l15*1032      + ic*32 + g4*8];
      const f16x8 a1 = *(const f16x8*)&Pc[(16+l15)*1032 + ic*32 + g4*8];
      acc1[0] = __builtin_amdgcn_mfma_f32_16x16x32_f16(a0, b, acc1[0], 0,0,0);
      acc1[1] = __builtin_amdgcn_mfma_f32_16x16x32_f16(a1, b, acc1[1], 0,0,0);
    }

    // ---- fc2 B prefetch: 12 chunks issued NOW (latency hides under epilogue's 3 barriers) ----
    const f16* bp2 = w2p + (size_t)(v*16 + wv)*16384 + lane*8;
    f16x8 pc2[12];
    #pragma unroll
    for (int j=0;j<12;++j) pc2[j] = *(const f16x8*)(bp2 + j*512);

    // ---- epilogue: bias + exact gelu + LN(256) ----
    const int c1 = wv*16 + l15;
    const float fb = fc1b[v*CHDIM + c1];
    const float lg = lng[v*CHDIM + c1], lb = lnb[v*CHDIM + c1];
    #pragma unroll
    for (int mf=0;mf<2;++mf)
      #pragma unroll
      for (int r=0;r<4;++r){
        const float h = acc1[mf][r] + fb;
        acc1[mf][r] = 0.5f*h*(1.f + erff(h*0.70710678118654752f));
      }
    #pragma unroll
    for (int mf=0;mf<2;++mf)
      #pragma unroll
      for (int r=0;r<4;++r){
        float s = acc1[mf][r], q = s*s;
        #pragma unroll
        for (int m=1;m<16;m<<=1){ s += __shfl_xor(s,m); q += __shfl_xor(q,m); }
        if (l15==0){ const int t = mf*16 + g4*4 + r; part[t][wv][0]=s; part[t][wv][1]=q; }
      }
    __syncthreads();
    if (tid < 32){
      float s=0.f, q=0.f;
      #pragma unroll
      for (int w=0;w<16;++w){ s += part[tid][w][0]; q += part[tid][w][1]; }
      const float mu = s*(1.f/CHDIM);
      musq[tid][0] = mu;
      musq[tid][1] = rsqrtf(q*(1.f/CHDIM) - mu*mu + 1e-5f);
    }
    __syncthreads();
    #pragma unroll
    for (int mf=0;mf<2;++mf)
      #pragma unroll
      for (int r=0;r<4;++r){
        const int t = mf*16 + g4*4 + r;
        hln[t*264 + c1] = (f16)((acc1[mf][r]-musq[t][0])*musq[t][1]*lg + lb);
      }
    __syncthreads();

    // ---- fc2: [32x256]x[256x1024]; wave = 64 cols (4 N-frags), both M-frags; full unroll ----
    f32x4 acc2[2][4];
    #pragma unroll
    for (int mf=0;mf<2;++mf)
      #pragma unroll
      for (int nf=0;nf<4;++nf) acc2[mf][nf] = fzero;
    f16x8 a0h, a1h;
    #pragma unroll
    for (int cki=0; cki<32; ++cki){
      const int ks = cki>>2, nf = cki&3;
      if (nf == 0){
        a0h = *(const f16x8*)&hln[l15*264      + ks*32 + g4*8];
        a1h = *(const f16x8*)&hln[(16+l15)*264 + ks*32 + g4*8];
      }
      const f16x8 b = pc2[cki%12];
      if (cki < 20) pc2[cki%12] = *(const f16x8*)(bp2 + (cki+12)*512);
      acc2[0][nf] = __builtin_amdgcn_mfma_f32_16x16x32_f16(a0h, b, acc2[0][nf], 0,0,0);
      acc2[1][nf] = __builtin_amdgcn_mfma_f32_16x16x32_f16(a1h, b, acc2[1][nf], 0,0,0);
    }
    // write O_v into Pc (+ terminal bias)
    #pragma unroll
    for (int mf=0;mf<2;++mf)
      #pragma unroll
      for (int nf=0;nf<4;++nf){
        const int c2 = wv*64 + nf*16 + l15;
        const float fb2 = (v==15) ? f2bias[c2] : 0.f;
        #pragma unroll
        for (int r=0;r<4;++r){
          const int t = mf*16 + g4*4 + r;
          Pc[t*1032 + c2] = (f16)(acc2[mf][nf][r] + fb2);
        }
      }
    __syncthreads();   // O_v visible before next stage / terminal write

    if (v == 15){
      #pragma unroll
      for (int p=0;p<4;++p){
        const int c = tid + p*1024, t = c>>7, c8 = (c&127)*8;
        const f16x8 val = *(const f16x8*)&Pc[t*1032 + c8];
        const size_t gi = (size_t)(tok0+t)*DDIM + c8;
        const float4 x0 = *(const float4*)(x+gi), x1 = *(const float4*)(x+gi+4);
        float4 o0, o1;
        o0.x = x0.x + (float)val[0]; o0.y = x0.y + (float)val[1];
        o0.z = x0.z + (float)val[2]; o0.w = x0.w + (float)val[3];
        o1.x = x1.x + (float)val[4]; o1.y = x1.y + (float)val[5];
        o1.z = x1.z + (float)val[6]; o1.w = x1.w + (float)val[7];
        *(float4*)(out+gi) = o0; *(float4*)(out+gi+4) = o1;
      }
    }
    f16* tmp = Pp; Pp = Pc; Pc = tmp;
  }
}

extern "C" void kernel_launch(void* const* d_in, const int* in_sizes, int n_in,
                              void* d_out, int out_size, void* d_ws, size_t ws_size,
                              hipStream_t stream) {
  (void)in_sizes; (void)n_in; (void)out_size; (void)ws_size;
  const float* x   = (const float*)d_in[0];
  const float* ng  = (const float*)d_in[1];
  const float* nb_ = (const float*)d_in[2];
  const float* w1  = (const float*)d_in[3];
  const float* f1b = (const float*)d_in[4];
  const float* lg  = (const float*)d_in[5];
  const float* lb  = (const float*)d_in[6];
  const float* w2  = (const float*)d_in[7];
  const float* f2b = (const float*)d_in[8];
  const float* rw  = (const float*)d_in[9];
  const float* rb  = (const float*)d_in[10];
  float* out = (float*)d_out;

  char* ws = (char*)d_ws;
  f16*  xnh  = (f16*)(ws);                                   // 16 MB
  f16*  w1p  = (f16*)(ws + 16777216);                        //  8 MB
  f16*  w2p  = (f16*)(ws + 16777216 + 8388608);              //  8 MB
  float* wsg = (float*)(ws + 16777216 + 8388608 + 8388608);  //  1 MB
  f16*  gouts= (f16*)(ws + 16777216 + 8388608 + 8388608 + 1048576); // 32 MB (O_0, O_1)

  k_prep<<<6144, 256, 0, stream>>>(x, ng, nb_, xnh, rw, rb, wsg, w1, w2, w1p, w2p);
  k_moe<<<256, 1024, 0, stream>>>(xnh, w1p, w2p, f1b, lg, lb, f2b, wsg, x, out, gouts);
}